// Round 1
// baseline (419.923 us; speedup 1.0000x reference)
//
#include <hip/hip_runtime.h>
#include <cmath>
#include <cstdint>

typedef unsigned short u16;
typedef __attribute__((ext_vector_type(8))) __bf16 bf16x8;
typedef __attribute__((ext_vector_type(4))) float f32x4;

// round-to-nearest-even fp32 -> bf16 bits
__device__ __forceinline__ u16 f2bf(float f) {
    union { float f; unsigned u; } v; v.f = f;
    unsigned r = v.u + 0x7fffu + ((v.u >> 16) & 1u);
    return (u16)(r >> 16);
}

// async global->LDS, 16B per lane. LDS dest must be wave-uniform base + lane*16.
__device__ __forceinline__ void gload_lds(const u16* g, u16* l) {
    __builtin_amdgcn_global_load_lds((__attribute__((address_space(1))) void*)g,
                                     (__attribute__((address_space(3))) void*)l,
                                     16, 0, 0);
}

// ---------------------------------------------------------------- prep kernels

__global__ __launch_bounds__(256) void x_to_bf16(const float4* __restrict__ X,
                                                 ushort4* __restrict__ Xb) {
    int i = blockIdx.x * 256 + threadIdx.x;
    float4 v = X[i];
    ushort4 o;
    o.x = f2bf(v.x); o.y = f2bf(v.y); o.z = f2bf(v.z); o.w = f2bf(v.w);
    Xb[i] = o;
}

// W_eff = W + 2 * B @ A  (LoRA folded); q additionally scaled by 0.125*log2(e)
__global__ __launch_bounds__(256) void prep_weff(
        const float* __restrict__ Wq, const float* __restrict__ Wk,
        const float* __restrict__ Wv, const float* __restrict__ Wo,
        const float* __restrict__ Aq, const float* __restrict__ Bq,
        const float* __restrict__ Ak, const float* __restrict__ Bk,
        const float* __restrict__ Av, const float* __restrict__ Bv,
        const float* __restrict__ Ao, const float* __restrict__ Bo,
        u16* __restrict__ Wqkv, u16* __restrict__ Wob) {
    const int p = blockIdx.y;
    const int idx = blockIdx.x * 256 + threadIdx.x;   // 0..1M
    const int n = idx >> 10, d = idx & 1023;
    const float* W; const float* A; const float* B;
    switch (p) {
        case 0: W = Wq; A = Aq; B = Bq; break;
        case 1: W = Wk; A = Ak; B = Bk; break;
        case 2: W = Wv; A = Av; B = Bv; break;
        default: W = Wo; A = Ao; B = Bo; break;
    }
    float lora = 0.f;
#pragma unroll
    for (int r = 0; r < 16; r++) lora += B[n * 16 + r] * A[r * 1024 + d];
    float v = W[idx] + 2.0f * lora;
    if (p == 0) v *= 0.125f * 1.44269504088896340736f;  // scaling * log2(e)
    if (p < 3) Wqkv[(size_t)p * 1048576 + idx] = f2bf(v);
    else       Wob[idx] = f2bf(v);
}

// ---------------------------------------------------------------- GEMM (m97-style)
// C[M x N] = A[M x 1024] @ B[N x 1024]^T, bf16 in, bf16 or fp32 out.
// 128x128 tile, 4 waves in 2x2, 4x4 16x16x32 MFMA per wave.
template <bool F32OUT>
__global__ __launch_bounds__(256) void gemm_bt(const u16* __restrict__ A,
                                               const u16* __restrict__ B,
                                               void* __restrict__ C, int ldc) {
    __shared__ __align__(16) u16 As[128 * 32];
    __shared__ __align__(16) u16 Bs[128 * 32];
    const int tid = threadIdx.x;
    const int lane = tid & 63, wave = tid >> 6;
    const int quad = lane >> 4, l16 = lane & 15;
    const int wm = (wave >> 1) * 64, wn = (wave & 1) * 64;
    const size_t m0 = (size_t)blockIdx.y * 128, n0 = (size_t)blockIdx.x * 128;
    const u16* Ap = A + m0 * 1024;
    const u16* Bp = B + n0 * 1024;
    f32x4 acc[4][4] = {};
    for (int k0 = 0; k0 < 1024; k0 += 32) {
#pragma unroll
        for (int hh = 0; hh < 2; hh++) {
            int c = tid + hh * 256;              // 512 16B chunks per tile
            int row = c >> 2, cp = (c & 3) * 8;  // row-major [128][32]
            gload_lds(Ap + (size_t)row * 1024 + k0 + cp, As + c * 8);
            gload_lds(Bp + (size_t)row * 1024 + k0 + cp, Bs + c * 8);
        }
        __syncthreads();
        bf16x8 af[4], bfr[4];
#pragma unroll
        for (int i = 0; i < 4; i++) {
            af[i]  = *(const bf16x8*)(As + (wm + i * 16 + l16) * 32 + quad * 8);
            bfr[i] = *(const bf16x8*)(Bs + (wn + i * 16 + l16) * 32 + quad * 8);
        }
#pragma unroll
        for (int mi = 0; mi < 4; mi++)
#pragma unroll
            for (int ni = 0; ni < 4; ni++)
                acc[mi][ni] = __builtin_amdgcn_mfma_f32_16x16x32_bf16(
                        af[mi], bfr[ni], acc[mi][ni], 0, 0, 0);
        __syncthreads();
    }
#pragma unroll
    for (int mi = 0; mi < 4; mi++)
#pragma unroll
        for (int ni = 0; ni < 4; ni++)
#pragma unroll
            for (int r = 0; r < 4; r++) {
                size_t row = m0 + wm + mi * 16 + quad * 4 + r;
                size_t col = n0 + wn + ni * 16 + l16;
                if (F32OUT) ((float*)C)[row * ldc + col] = acc[mi][ni][r];
                else        ((u16*)C)[row * ldc + col] = f2bf(acc[mi][ni][r]);
            }
}

// ---------------------------------------------------------------- V transpose
// Y[:,2048:3072] (V, [4096][1024] within [4096][3072]) -> Vt [1024][4096]
__global__ __launch_bounds__(256) void transpose_v(const u16* __restrict__ Y,
                                                   u16* __restrict__ Vt) {
    __shared__ u16 tile[64][68];
    const int dv0 = blockIdx.x * 64;
    const int t0  = blockIdx.y * 64;
    const int tid = threadIdx.x;
#pragma unroll
    for (int p = 0; p < 4; p++) {
        int pos = tid + p * 256;
        int row = pos >> 4;           // t-local
        int c4  = (pos & 15) * 4;     // dv-local
        ushort4 v = *(const ushort4*)(Y + (size_t)(t0 + row) * 3072 + 2048 + dv0 + c4);
        tile[row][c4 + 0] = v.x; tile[row][c4 + 1] = v.y;
        tile[row][c4 + 2] = v.z; tile[row][c4 + 3] = v.w;
    }
    __syncthreads();
#pragma unroll
    for (int p = 0; p < 4; p++) {
        int pos = tid + p * 256;
        int orow = pos >> 4;          // dv-local
        int oc4  = (pos & 15) * 4;    // t-local
        ushort4 o;
        o.x = tile[oc4 + 0][orow]; o.y = tile[oc4 + 1][orow];
        o.z = tile[oc4 + 2][orow]; o.w = tile[oc4 + 3][orow];
        *(ushort4*)(Vt + (size_t)(dv0 + orow) * 4096 + t0 + oc4) = o;
    }
}

// ---------------------------------------------------------------- flash attention
// Q pre-scaled by 0.125*log2e (folded into Wq_eff) -> use exp2.
// Block: head h, 128 q-rows; 4 waves x 32 rows. K-tiles of 64, causal skip.
__global__ __launch_bounds__(256) void flash_attn(const u16* __restrict__ Y,   // [4096][3072] q|k|v
                                                  const u16* __restrict__ Vt,  // [1024][4096]
                                                  u16* __restrict__ O) {       // [4096][1024]
    __shared__ __align__(16) u16 Ks[64 * 64];       // [s][d]
    __shared__ __align__(16) u16 Vs[64 * 64];       // [d][s]
    __shared__ __align__(16) u16 Ps[4][32 * 64];    // per-wave P
    const int h = blockIdx.x;
    const int qb = (int)gridDim.y - 1 - (int)blockIdx.y;  // big blocks first
    const int q0 = qb * 128;
    const int tid = threadIdx.x;
    const int wave = tid >> 6, lane = tid & 63;
    const int quad = lane >> 4, l16 = lane & 15;

    // Q fragments in registers (A-layout)
    bf16x8 qf[2][2];
#pragma unroll
    for (int mi = 0; mi < 2; mi++)
#pragma unroll
        for (int kf = 0; kf < 2; kf++)
            qf[mi][kf] = *(const bf16x8*)(Y + (size_t)(q0 + wave * 32 + mi * 16 + l16) * 3072
                                            + h * 64 + kf * 32 + quad * 8);

    f32x4 oacc[2][4] = {};
    float m_i[2][4], l_i[2][4];
#pragma unroll
    for (int mi = 0; mi < 2; mi++)
#pragma unroll
        for (int r = 0; r < 4; r++) { m_i[mi][r] = -INFINITY; l_i[mi][r] = 0.f; }

    const u16* Kbase = Y + 1024 + h * 64;
    const u16* Vbase = Vt + (size_t)(h * 64) * 4096;
    const int nIter = 2 * qb + 2;

    for (int it = 0; it < nIter; it++) {
        const int s0 = it * 64;
#pragma unroll
        for (int hh = 0; hh < 2; hh++) {
            int c = tid + hh * 256;
            int row = c >> 3, cp = (c & 7) * 8;
            gload_lds(Kbase + (size_t)(s0 + row) * 3072 + cp, Ks + c * 8);
            gload_lds(Vbase + (size_t)row * 4096 + s0 + cp,   Vs + c * 8);
        }
        __syncthreads();

        // S = Q K^T
        bf16x8 kfr[4][2];
#pragma unroll
        for (int ni = 0; ni < 4; ni++)
#pragma unroll
            for (int kf = 0; kf < 2; kf++)
                kfr[ni][kf] = *(const bf16x8*)(Ks + (ni * 16 + l16) * 64 + kf * 32 + quad * 8);
        f32x4 sacc[2][4] = {};
#pragma unroll
        for (int mi = 0; mi < 2; mi++)
#pragma unroll
            for (int ni = 0; ni < 4; ni++) {
                sacc[mi][ni] = __builtin_amdgcn_mfma_f32_16x16x32_bf16(
                        qf[mi][0], kfr[ni][0], sacc[mi][ni], 0, 0, 0);
                sacc[mi][ni] = __builtin_amdgcn_mfma_f32_16x16x32_bf16(
                        qf[mi][1], kfr[ni][1], sacc[mi][ni], 0, 0, 0);
            }

        // causal mask + online softmax (rows = quad*4+r; cols across 16 lanes)
        float pv[2][4][4];
#pragma unroll
        for (int mi = 0; mi < 2; mi++) {
            const int qrb = q0 + wave * 32 + mi * 16 + quad * 4;
#pragma unroll
            for (int r = 0; r < 4; r++) {
                const int qg = qrb + r;
                float mx = -INFINITY;
#pragma unroll
                for (int ni = 0; ni < 4; ni++) {
                    int sg = s0 + ni * 16 + l16;
                    float v = sacc[mi][ni][r];
                    v = (sg <= qg) ? v : -INFINITY;
                    pv[mi][ni][r] = v;
                    mx = fmaxf(mx, v);
                }
#pragma unroll
                for (int off = 1; off < 16; off <<= 1)
                    mx = fmaxf(mx, __shfl_xor(mx, off, 64));
                float mold = m_i[mi][r];
                float mnew = fmaxf(mold, mx);
                float alpha = exp2f(mold - mnew);
                m_i[mi][r] = mnew;
                float rs = 0.f;
#pragma unroll
                for (int ni = 0; ni < 4; ni++) {
                    float pe = exp2f(pv[mi][ni][r] - mnew);
                    pv[mi][ni][r] = pe;
                    rs += pe;
                }
#pragma unroll
                for (int off = 1; off < 16; off <<= 1)
                    rs += __shfl_xor(rs, off, 64);
                l_i[mi][r] = l_i[mi][r] * alpha + rs;
#pragma unroll
                for (int nj = 0; nj < 4; nj++) oacc[mi][nj][r] *= alpha;
            }
        }

        // P: C-layout -> LDS -> A-layout (wave-private region, lgkm drain only)
#pragma unroll
        for (int mi = 0; mi < 2; mi++)
#pragma unroll
            for (int ni = 0; ni < 4; ni++)
#pragma unroll
                for (int r = 0; r < 4; r++)
                    Ps[wave][(mi * 16 + quad * 4 + r) * 64 + ni * 16 + l16] =
                            f2bf(pv[mi][ni][r]);
        asm volatile("s_waitcnt lgkmcnt(0)" ::: "memory");

        // O += P @ V
        bf16x8 pf[2][2], vf[4][2];
#pragma unroll
        for (int mi = 0; mi < 2; mi++)
#pragma unroll
            for (int kf = 0; kf < 2; kf++)
                pf[mi][kf] = *(const bf16x8*)(Ps[wave] + (mi * 16 + l16) * 64 + kf * 32 + quad * 8);
#pragma unroll
        for (int nj = 0; nj < 4; nj++)
#pragma unroll
            for (int kf = 0; kf < 2; kf++)
                vf[nj][kf] = *(const bf16x8*)(Vs + (nj * 16 + l16) * 64 + kf * 32 + quad * 8);
#pragma unroll
        for (int mi = 0; mi < 2; mi++)
#pragma unroll
            for (int nj = 0; nj < 4; nj++) {
                oacc[mi][nj] = __builtin_amdgcn_mfma_f32_16x16x32_bf16(
                        pf[mi][0], vf[nj][0], oacc[mi][nj], 0, 0, 0);
                oacc[mi][nj] = __builtin_amdgcn_mfma_f32_16x16x32_bf16(
                        pf[mi][1], vf[nj][1], oacc[mi][nj], 0, 0, 0);
            }
        __syncthreads();   // all waves done with Ks/Vs before next staging
    }

    // epilogue: O = oacc / l
#pragma unroll
    for (int mi = 0; mi < 2; mi++)
#pragma unroll
        for (int r = 0; r < 4; r++) {
            const float inv = 1.f / l_i[mi][r];
            const int qg = q0 + wave * 32 + mi * 16 + quad * 4 + r;
#pragma unroll
            for (int nj = 0; nj < 4; nj++)
                O[(size_t)qg * 1024 + h * 64 + nj * 16 + l16] =
                        f2bf(oacc[mi][nj][r] * inv);
        }
}

// ---------------------------------------------------------------- launch

extern "C" void kernel_launch(void* const* d_in, const int* in_sizes, int n_in,
                              void* d_out, int out_size, void* d_ws, size_t ws_size,
                              hipStream_t stream) {
    const float* X  = (const float*)d_in[0];
    // d_in[1] = attention_mask: exactly causal, reconstructed analytically.
    const float* Wq = (const float*)d_in[2];
    const float* Wk = (const float*)d_in[3];
    const float* Wv = (const float*)d_in[4];
    const float* Wo = (const float*)d_in[5];
    const float* Aq = (const float*)d_in[6];
    const float* Bq = (const float*)d_in[7];
    const float* Ak = (const float*)d_in[8];
    const float* Bk = (const float*)d_in[9];
    const float* Av = (const float*)d_in[10];
    const float* Bv = (const float*)d_in[11];
    const float* Ao = (const float*)d_in[12];
    const float* Bo = (const float*)d_in[13];

    char* ws = (char*)d_ws;
    u16* Xb   = (u16*)(ws);                       // 8 MB  [4096][1024]
    u16* Wqkv = (u16*)(ws + (8u  << 20));         // 6 MB  [3072][1024]
    u16* Wob  = (u16*)(ws + (14u << 20));         // 2 MB  [1024][1024]
    u16* Y    = (u16*)(ws + (16u << 20));         // 24 MB [4096][3072] q|k|v
    u16* Vt   = (u16*)(ws + (40u << 20));         // 8 MB  [1024][4096]
    u16* Ob   = (u16*)(ws + (48u << 20));         // 8 MB  [4096][1024]  (56 MB total)

    x_to_bf16<<<4096, 256, 0, stream>>>((const float4*)X, (ushort4*)Xb);
    prep_weff<<<dim3(4096, 4), 256, 0, stream>>>(Wq, Wk, Wv, Wo, Aq, Bq, Ak, Bk,
                                                 Av, Bv, Ao, Bo, Wqkv, Wob);
    gemm_bt<false><<<dim3(24, 32), 256, 0, stream>>>(Xb, Wqkv, Y, 3072);
    transpose_v<<<dim3(16, 64), 256, 0, stream>>>(Y, Vt);
    flash_attn<<<dim3(16, 32), 256, 0, stream>>>(Y, Vt, Ob);
    gemm_bt<true><<<dim3(8, 32), 256, 0, stream>>>(Ob, Wob, d_out, 1024);
}

// Round 2
// 323.593 us; speedup vs baseline: 1.2977x; 1.2977x over previous
//
#include <hip/hip_runtime.h>
#include <cmath>
#include <cstdint>

typedef unsigned short u16;
typedef __attribute__((ext_vector_type(8))) __bf16 bf16x8;
typedef __attribute__((ext_vector_type(4))) __bf16 bf16x4;
typedef __attribute__((ext_vector_type(4))) short s16x4;
typedef __attribute__((ext_vector_type(4))) float f32x4;

// round-to-nearest-even fp32 -> bf16 bits
__device__ __forceinline__ u16 f2bf(float f) {
    union { float f; unsigned u; } v; v.f = f;
    unsigned r = v.u + 0x7fffu + ((v.u >> 16) & 1u);
    return (u16)(r >> 16);
}

// async global->LDS, 16B per lane. LDS dest must be wave-uniform base + lane*16.
__device__ __forceinline__ void gload_lds(const u16* g, u16* l) {
    __builtin_amdgcn_global_load_lds((__attribute__((address_space(1))) void*)g,
                                     (__attribute__((address_space(3))) void*)l,
                                     16, 0, 0);
}

// 16x16x16 bf16 MFMA (legacy shape; A/B = 4 bf16 at k=quad*4+j)
__device__ __forceinline__ f32x4 mfma16(s16x4 a, s16x4 b, f32x4 c) {
#if __has_builtin(__builtin_amdgcn_mfma_f32_16x16x16bf16_1k)
    return __builtin_amdgcn_mfma_f32_16x16x16bf16_1k(a, b, c, 0, 0, 0);
#else
    asm("v_mfma_f32_16x16x16_bf16 %0, %1, %2, %3"
        : "=v"(c) : "v"(a), "v"(b), "0"(c));
    return c;
#endif
}

// ---------------------------------------------------------------- prep kernels

__global__ __launch_bounds__(256) void x_to_bf16(const float4* __restrict__ X,
                                                 ushort4* __restrict__ Xb) {
    int i = blockIdx.x * 256 + threadIdx.x;
    float4 v = X[i];
    ushort4 o;
    o.x = f2bf(v.x); o.y = f2bf(v.y); o.z = f2bf(v.z); o.w = f2bf(v.w);
    Xb[i] = o;
}

// W_eff = W + 2 * B @ A  (LoRA folded); q additionally scaled by 0.125*log2(e)
__global__ __launch_bounds__(256) void prep_weff(
        const float* __restrict__ Wq, const float* __restrict__ Wk,
        const float* __restrict__ Wv, const float* __restrict__ Wo,
        const float* __restrict__ Aq, const float* __restrict__ Bq,
        const float* __restrict__ Ak, const float* __restrict__ Bk,
        const float* __restrict__ Av, const float* __restrict__ Bv,
        const float* __restrict__ Ao, const float* __restrict__ Bo,
        u16* __restrict__ Wqkv, u16* __restrict__ Wob) {
    const int p = blockIdx.y;
    const int idx = blockIdx.x * 256 + threadIdx.x;   // 0..1M
    const int n = idx >> 10, d = idx & 1023;
    const float* W; const float* A; const float* B;
    switch (p) {
        case 0: W = Wq; A = Aq; B = Bq; break;
        case 1: W = Wk; A = Ak; B = Bk; break;
        case 2: W = Wv; A = Av; B = Bv; break;
        default: W = Wo; A = Ao; B = Bo; break;
    }
    float lora = 0.f;
#pragma unroll
    for (int r = 0; r < 16; r++) lora += B[n * 16 + r] * A[r * 1024 + d];
    float v = W[idx] + 2.0f * lora;
    if (p == 0) v *= 0.125f * 1.44269504088896340736f;  // scaling * log2(e)
    if (p < 3) Wqkv[(size_t)p * 1048576 + idx] = f2bf(v);
    else       Wob[idx] = f2bf(v);
}

// ---------------------------------------------------------------- GEMM (m97-style)
// C[M x N] = A[M x 1024] @ B[N x 1024]^T, bf16 in, bf16 or fp32 out.
template <bool F32OUT>
__global__ __launch_bounds__(256) void gemm_bt(const u16* __restrict__ A,
                                               const u16* __restrict__ B,
                                               void* __restrict__ C, int ldc) {
    __shared__ __align__(16) u16 As[128 * 32];
    __shared__ __align__(16) u16 Bs[128 * 32];
    const int tid = threadIdx.x;
    const int lane = tid & 63, wave = tid >> 6;
    const int quad = lane >> 4, l16 = lane & 15;
    const int wm = (wave >> 1) * 64, wn = (wave & 1) * 64;
    const size_t m0 = (size_t)blockIdx.y * 128, n0 = (size_t)blockIdx.x * 128;
    const u16* Ap = A + m0 * 1024;
    const u16* Bp = B + n0 * 1024;
    f32x4 acc[4][4] = {};
    for (int k0 = 0; k0 < 1024; k0 += 32) {
#pragma unroll
        for (int hh = 0; hh < 2; hh++) {
            int c = tid + hh * 256;              // 512 16B chunks per tile
            int row = c >> 2, cp = (c & 3) * 8;  // row-major [128][32]
            gload_lds(Ap + (size_t)row * 1024 + k0 + cp, As + c * 8);
            gload_lds(Bp + (size_t)row * 1024 + k0 + cp, Bs + c * 8);
        }
        __syncthreads();
        bf16x8 af[4], bfr[4];
#pragma unroll
        for (int i = 0; i < 4; i++) {
            af[i]  = *(const bf16x8*)(As + (wm + i * 16 + l16) * 32 + quad * 8);
            bfr[i] = *(const bf16x8*)(Bs + (wn + i * 16 + l16) * 32 + quad * 8);
        }
#pragma unroll
        for (int mi = 0; mi < 4; mi++)
#pragma unroll
            for (int ni = 0; ni < 4; ni++)
                acc[mi][ni] = __builtin_amdgcn_mfma_f32_16x16x32_bf16(
                        af[mi], bfr[ni], acc[mi][ni], 0, 0, 0);
        __syncthreads();
    }
#pragma unroll
    for (int mi = 0; mi < 4; mi++)
#pragma unroll
        for (int ni = 0; ni < 4; ni++)
#pragma unroll
            for (int r = 0; r < 4; r++) {
                size_t row = m0 + wm + mi * 16 + quad * 4 + r;
                size_t col = n0 + wn + ni * 16 + l16;
                if (F32OUT) ((float*)C)[row * ldc + col] = acc[mi][ni][r];
                else        ((u16*)C)[row * ldc + col] = f2bf(acc[mi][ni][r]);
            }
}

// ---------------------------------------------------------------- V transpose
// Y[:,2048:3072] (V, [4096][1024] within [4096][3072]) -> Vt [1024][4096]
__global__ __launch_bounds__(256) void transpose_v(const u16* __restrict__ Y,
                                                   u16* __restrict__ Vt) {
    __shared__ u16 tile[64][68];
    const int dv0 = blockIdx.x * 64;
    const int t0  = blockIdx.y * 64;
    const int tid = threadIdx.x;
#pragma unroll
    for (int p = 0; p < 4; p++) {
        int pos = tid + p * 256;
        int row = pos >> 4;           // t-local
        int c4  = (pos & 15) * 4;     // dv-local
        ushort4 v = *(const ushort4*)(Y + (size_t)(t0 + row) * 3072 + 2048 + dv0 + c4);
        tile[row][c4 + 0] = v.x; tile[row][c4 + 1] = v.y;
        tile[row][c4 + 2] = v.z; tile[row][c4 + 3] = v.w;
    }
    __syncthreads();
#pragma unroll
    for (int p = 0; p < 4; p++) {
        int pos = tid + p * 256;
        int orow = pos >> 4;          // dv-local
        int oc4  = (pos & 15) * 4;    // t-local
        ushort4 o;
        o.x = tile[oc4 + 0][orow]; o.y = tile[oc4 + 1][orow];
        o.z = tile[oc4 + 2][orow]; o.w = tile[oc4 + 3][orow];
        *(ushort4*)(Vt + (size_t)(dv0 + orow) * 4096 + t0 + oc4) = o;
    }
}

// ---------------------------------------------------------------- flash attention
// S^T formulation: S^T = MFMA(A=K, B=Q) so softmax reduces over quad/reg dims
// (2 shuffles) and P^T registers feed PV directly as 16x16x16 A-operands.
// K/V staged into LDS with chunk-XOR swizzle to kill bank conflicts.
// Block = 128 threads (2 waves), 64 q-rows; grid (16 heads, 64 qb) big-first.
__global__ __launch_bounds__(128) void flash_attn(const u16* __restrict__ Y,   // [4096][3072] q|k|v
                                                  const u16* __restrict__ Vt,  // [1024][4096]
                                                  u16* __restrict__ O) {       // [4096][1024]
    __shared__ __align__(16) u16 Ks[64 * 64];   // [s][d], chunk-swizzled
    __shared__ __align__(16) u16 Vs[64 * 64];   // [dv][s], chunk-swizzled
    const int h = blockIdx.x;
    const int qb = (int)gridDim.y - 1 - (int)blockIdx.y;  // big blocks first
    const int q0 = qb * 64;
    const int tid = threadIdx.x;               // 0..127
    const int wave = tid >> 6, lane = tid & 63;
    const int quad = lane >> 4, l16 = lane & 15;

    // Q as B-operand fragments: B[n=q=l16][k=d=quad*8+j]
    bf16x8 qf[2][2];
#pragma unroll
    for (int mi = 0; mi < 2; mi++)
#pragma unroll
        for (int kf = 0; kf < 2; kf++)
            qf[mi][kf] = *(const bf16x8*)(Y + (size_t)(q0 + wave * 32 + mi * 16 + l16) * 3072
                                            + h * 64 + kf * 32 + quad * 8);

    f32x4 oacc[2][4] = {};                     // D[q(row)=quad*4+r][dv(col)=l16]
    float m_i[2] = {-INFINITY, -INFINITY};     // per-lane state for q = l16 column
    float l_i[2] = {0.f, 0.f};

    const u16* Kbase = Y + 1024 + (size_t)h * 64;
    const u16* Vbase = Vt + (size_t)(h * 64) * 4096;
    const int nIter = qb + 1;

    for (int it = 0; it < nIter; it++) {
        const int s0 = it * 64;
        // stage K[s][d] and V[dv][s] tiles, 16B chunks, XOR-swizzled placement
#pragma unroll
        for (int hh = 0; hh < 4; hh++) {
            int idx = hh * 128 + tid;              // 0..511 LDS chunk slot
            int row = idx >> 3;
            int cg  = (idx & 7) ^ (row & 7);       // source chunk for this slot
            gload_lds(Kbase + (size_t)(s0 + row) * 3072 + cg * 8, Ks + idx * 8);
            gload_lds(Vbase + (size_t)row * 4096 + s0 + cg * 8,   Vs + idx * 8);
        }
        __syncthreads();

        // S^T[s][q] = K Q^T : A = K fragment, B = Q fragment
        f32x4 sacc[2][4] = {};
#pragma unroll
        for (int ni = 0; ni < 4; ni++) {
            int row = ni * 16 + l16;               // s-local
            bf16x8 k0 = *(const bf16x8*)(Ks + (row * 8 + (quad ^ (l16 & 7))) * 8);
            bf16x8 k1 = *(const bf16x8*)(Ks + (row * 8 + ((4 + quad) ^ (l16 & 7))) * 8);
#pragma unroll
            for (int mi = 0; mi < 2; mi++) {
                sacc[mi][ni] = __builtin_amdgcn_mfma_f32_16x16x32_bf16(
                        k0, qf[mi][0], sacc[mi][ni], 0, 0, 0);
                sacc[mi][ni] = __builtin_amdgcn_mfma_f32_16x16x32_bf16(
                        k1, qf[mi][1], sacc[mi][ni], 0, 0, 0);
            }
        }

        // online softmax over s (quad/reg dims); state indexed by q = l16
        const bool maskit = (it == nIter - 1);     // only diagonal tile needs mask
        s16x4 pf[2][4];
        float ar[2][4];
#pragma unroll
        for (int mi = 0; mi < 2; mi++) {
            const int qg = q0 + wave * 32 + mi * 16 + l16;
            if (maskit) {
#pragma unroll
                for (int ni = 0; ni < 4; ni++)
#pragma unroll
                    for (int r = 0; r < 4; r++) {
                        int sg = s0 + ni * 16 + quad * 4 + r;
                        if (sg > qg) sacc[mi][ni][r] = -INFINITY;
                    }
            }
            float mx = -INFINITY;
#pragma unroll
            for (int ni = 0; ni < 4; ni++)
#pragma unroll
                for (int r = 0; r < 4; r++) mx = fmaxf(mx, sacc[mi][ni][r]);
            mx = fmaxf(mx, __shfl_xor(mx, 16));
            mx = fmaxf(mx, __shfl_xor(mx, 32));
            float mnew = fmaxf(m_i[mi], mx);
            float alpha = __builtin_amdgcn_exp2f(m_i[mi] - mnew);
            m_i[mi] = mnew;
            float rs = 0.f;
#pragma unroll
            for (int ni = 0; ni < 4; ni++)
#pragma unroll
                for (int r = 0; r < 4; r++) {
                    float pe = __builtin_amdgcn_exp2f(sacc[mi][ni][r] - mnew);
                    sacc[mi][ni][r] = pe;
                    rs += pe;
                }
            rs += __shfl_xor(rs, 16);
            rs += __shfl_xor(rs, 32);
            l_i[mi] = l_i[mi] * alpha + rs;
#pragma unroll
            for (int ni = 0; ni < 4; ni++) {
                bf16x4 t = { (__bf16)sacc[mi][ni][0], (__bf16)sacc[mi][ni][1],
                             (__bf16)sacc[mi][ni][2], (__bf16)sacc[mi][ni][3] };
                pf[mi][ni] = __builtin_bit_cast(s16x4, t);
            }
            // alpha lives per l16(q); O rows are quad*4+r -> broadcast
#pragma unroll
            for (int r = 0; r < 4; r++) ar[mi][r] = __shfl(alpha, quad * 4 + r);
#pragma unroll
            for (int nj = 0; nj < 4; nj++)
#pragma unroll
                for (int r = 0; r < 4; r++) oacc[mi][nj][r] *= ar[mi][r];
        }

        // O += P V : A = P^T regs (k=quad*4+j), B = V from swizzled Vs[dv][s]
#pragma unroll
        for (int ni = 0; ni < 4; ni++) {
            const int scnk = ni * 2 + (quad >> 1);
#pragma unroll
            for (int nj = 0; nj < 4; nj++) {
                int dvrow = nj * 16 + l16;
                s16x4 vf = *(const s16x4*)(Vs + (dvrow * 8 + (scnk ^ (l16 & 7))) * 8
                                              + (quad & 1) * 4);
                oacc[0][nj] = mfma16(pf[0][ni], vf, oacc[0][nj]);
                oacc[1][nj] = mfma16(pf[1][ni], vf, oacc[1][nj]);
            }
        }
        __syncthreads();
    }

    // epilogue: O = oacc / l  (l indexed by l16 -> broadcast to rows)
#pragma unroll
    for (int mi = 0; mi < 2; mi++) {
        float inv = 1.0f / l_i[mi];
#pragma unroll
        for (int r = 0; r < 4; r++) {
            float ir = __shfl(inv, quad * 4 + r);
            const int qg = q0 + wave * 32 + mi * 16 + quad * 4 + r;
#pragma unroll
            for (int nj = 0; nj < 4; nj++)
                O[(size_t)qg * 1024 + h * 64 + nj * 16 + l16] =
                        f2bf(oacc[mi][nj][r] * ir);
        }
    }
}

// ---------------------------------------------------------------- launch

extern "C" void kernel_launch(void* const* d_in, const int* in_sizes, int n_in,
                              void* d_out, int out_size, void* d_ws, size_t ws_size,
                              hipStream_t stream) {
    const float* X  = (const float*)d_in[0];
    // d_in[1] = attention_mask: exactly causal, reconstructed analytically.
    const float* Wq = (const float*)d_in[2];
    const float* Wk = (const float*)d_in[3];
    const float* Wv = (const float*)d_in[4];
    const float* Wo = (const float*)d_in[5];
    const float* Aq = (const float*)d_in[6];
    const float* Bq = (const float*)d_in[7];
    const float* Ak = (const float*)d_in[8];
    const float* Bk = (const float*)d_in[9];
    const float* Av = (const float*)d_in[10];
    const float* Bv = (const float*)d_in[11];
    const float* Ao = (const float*)d_in[12];
    const float* Bo = (const float*)d_in[13];

    char* ws = (char*)d_ws;
    u16* Xb   = (u16*)(ws);                       // 8 MB  [4096][1024]
    u16* Wqkv = (u16*)(ws + (8u  << 20));         // 6 MB  [3072][1024]
    u16* Wob  = (u16*)(ws + (14u << 20));         // 2 MB  [1024][1024]
    u16* Y    = (u16*)(ws + (16u << 20));         // 24 MB [4096][3072] q|k|v
    u16* Vt   = (u16*)(ws + (40u << 20));         // 8 MB  [1024][4096]
    u16* Ob   = (u16*)(ws + (48u << 20));         // 8 MB  [4096][1024]  (56 MB total)

    x_to_bf16<<<4096, 256, 0, stream>>>((const float4*)X, (ushort4*)Xb);
    prep_weff<<<dim3(4096, 4), 256, 0, stream>>>(Wq, Wk, Wv, Wo, Aq, Bq, Ak, Bk,
                                                 Av, Bv, Ao, Bo, Wqkv, Wob);
    gemm_bt<false><<<dim3(24, 32), 256, 0, stream>>>(Xb, Wqkv, Y, 3072);
    transpose_v<<<dim3(16, 64), 256, 0, stream>>>(Y, Vt);
    flash_attn<<<dim3(16, 64), 128, 0, stream>>>(Y, Vt, Ob);
    gemm_bt<true><<<dim3(8, 32), 256, 0, stream>>>(Ob, Wob, d_out, 1024);
}